// Round 11
// baseline (143.580 us; speedup 1.0000x reference)
//
#include <hip/hip_runtime.h>
#include <stdint.h>

using i32x4  = __attribute__((ext_vector_type(4))) int;
using i32x16 = __attribute__((ext_vector_type(16))) int;

// ---------------- ws layout ----------------
#define WS_SCALEF   2056
#define WS_QW       (1u << 20)

// ---------------- kernel 1: wabs partial sums (deterministic) ----------------
__global__ __launch_bounds__(256) void k_wpart(const float* __restrict__ w,
                                               double* __restrict__ partials) {
    int t = threadIdx.x;
    int b = blockIdx.x;
    const float4* w4 = (const float4*)(w + b * 4096);
    double s = 0.0;
#pragma unroll
    for (int i = 0; i < 4; ++i) {
        float4 v = w4[i * 256 + t];
        s += (double)fabsf(v.x) + (double)fabsf(v.y) +
             (double)fabsf(v.z) + (double)fabsf(v.w);
    }
#pragma unroll
    for (int off = 32; off > 0; off >>= 1) s += __shfl_down(s, off, 64);
    __shared__ double lds[4];
    if ((t & 63) == 0) lds[t >> 6] = s;
    __syncthreads();
    if (t == 0) partials[b] = ((lds[0] + lds[1]) + (lds[2] + lds[3]));
}

// ---------------- kernel 2: fused scale-reduce (redundant, deterministic) + wquant ----
__global__ __launch_bounds__(256) void k_wquant(const float* __restrict__ w,
                                                const double* __restrict__ partials,
                                                int8_t* __restrict__ qw,
                                                float* __restrict__ scale_f) {
    int t = threadIdx.x;
    double s = partials[t];
#pragma unroll
    for (int off = 32; off > 0; off >>= 1) s += __shfl_down(s, off, 64);
    __shared__ double lds[4];
    if ((t & 63) == 0) lds[t >> 6] = s;
    __syncthreads();
    __shared__ double sc_sh;
    if (t == 0) {
        double m = ((lds[0] + lds[1]) + (lds[2] + lds[3])) / 1048576.0;
        if (m < 1e-5) m = 1e-5;
        sc_sh = m;
        if (blockIdx.x == 0) *scale_f = (float)m;
    }
    __syncthreads();
    double half_s = 0.5 * sc_sh;

    int idx = blockIdx.x * 2048 + t * 8;
    float4 v0 = *(const float4*)(w + idx);
    float4 v1 = *(const float4*)(w + idx + 4);
    float f[8] = {v0.x, v0.y, v0.z, v0.w, v1.x, v1.y, v1.z, v1.w};
    union { char c[8]; int2 p; } u;
#pragma unroll
    for (int i = 0; i < 8; ++i) {
        char q = 0;
        if ((double)fabsf(f[i]) > half_s) q = (f[i] > 0.0f) ? 1 : -1;
        u.c[i] = q;
    }
    *(int2*)(qw + idx) = u.p;
}

// ---------------- kernel 3: MEGA — in-block activation quant + barrier-free i8 GEMM ----
// 256 blocks (1/CU), 512 thr (8 waves, 2M x 4N, per-wave 64x64 per column-chunk).
// Phase 1: quantize own 128x1024 x-panel -> LDS Ap (int8, slot-XOR swizzle), fact -> LDS.
// Phase 2: ONE __syncthreads, then 64 unrolled K-steps (BK=64, 4 chunks of N=256):
//   A: ds_read_b128 from persistent Ap (slot uses kt = G & 15 — K restarts per chunk);
//   B: global int4 loads (L2-resident, 1-deep reg prefetch);
//   8 x mfma_i32_32x32x32 per step; no barriers; per-chunk fire-and-forget stores.

__device__ inline int q8pack(float4 f, float as) {
    int a = (int)fminf(fmaxf(rintf(f.x * as), -128.0f), 127.0f);
    int b = (int)fminf(fmaxf(rintf(f.y * as), -128.0f), 127.0f);
    int c = (int)fminf(fmaxf(rintf(f.z * as), -128.0f), 127.0f);
    int d = (int)fminf(fmaxf(rintf(f.w * as), -128.0f), 127.0f);
    return (a & 0xff) | ((b & 0xff) << 8) | ((c & 0xff) << 16) | ((d & 0xff) << 24);
}

__global__ __launch_bounds__(512, 2) void k_mega(const float* __restrict__ x,
                                                 const int8_t* __restrict__ Bq,
                                                 const float* __restrict__ scale_f,
                                                 const float* __restrict__ bias,
                                                 float* __restrict__ out) {
    __shared__ int8_t Ap[131072];           // 128 rows x 1024 K, swizzled
    __shared__ float factsh[128];

    const int tid  = threadIdx.x;
    const int lane = tid & 63;
    const int wid  = tid >> 6;              // 0..7
    const int wm   = wid >> 2;              // 0..1
    const int wn   = wid & 3;               // 0..3
    const int l31  = lane & 31;
    const int l5   = lane >> 5;
    const int tm   = blockIdx.x;            // 0..255

    // ---- phase 1: per-row absmax quant of own x-panel ----
    const float* xb = x + (size_t)tm * 131072;
#pragma unroll
    for (int i = 0; i < 16; ++i) {
        int row = wid * 16 + i;
        const float4* xr = (const float4*)(xb + (size_t)row * 1024) + lane * 4;
        float4 v0 = xr[0], v1 = xr[1], v2 = xr[2], v3 = xr[3];
        float m = fmaxf(fmaxf(fmaxf(fabsf(v0.x), fabsf(v0.y)), fmaxf(fabsf(v0.z), fabsf(v0.w))),
                        fmaxf(fmaxf(fabsf(v1.x), fabsf(v1.y)), fmaxf(fabsf(v1.z), fabsf(v1.w))));
        m = fmaxf(m, fmaxf(fmaxf(fabsf(v2.x), fabsf(v2.y)), fmaxf(fabsf(v2.z), fabsf(v2.w))));
        m = fmaxf(m, fmaxf(fmaxf(fabsf(v3.x), fabsf(v3.y)), fmaxf(fabsf(v3.z), fabsf(v3.w))));
#pragma unroll
        for (int off = 32; off > 0; off >>= 1) m = fmaxf(m, __shfl_xor(m, off, 64));
        m = fmaxf(m, 1e-5f);
        float as = 127.0f / m;
        i32x4 pk;
        pk[0] = q8pack(v0, as); pk[1] = q8pack(v1, as);
        pk[2] = q8pack(v2, as); pk[3] = q8pack(v3, as);
        *(i32x4*)(Ap + row * 1024 + ((lane ^ (row & 7)) << 4)) = pk;
        if (lane == 0) factsh[row] = 1.0f / as;
    }
    __syncthreads();                        // the only block-wide barrier

    // ---- phase 2: GEMM ----
    const float sc = *scale_f;
    i32x4 aB[2][2][2], bB[2][2][2];         // [bank][mt|nt][ks]
    i32x16 acc[2][2];

    auto LDA = [&](int G, int bank) {
        const int kt = G & 15;              // K-tile restarts each column-chunk
#pragma unroll
        for (int mt = 0; mt < 2; ++mt)
#pragma unroll
            for (int ks = 0; ks < 2; ++ks) {
                int r = wm * 64 + mt * 32 + l31;
                int slot = (kt * 4 + ks * 2 + l5) ^ (r & 7);
                aB[bank][mt][ks] = *(const i32x4*)(Ap + r * 1024 + (slot << 4));
            }
    };
    auto LDB = [&](int G, int bank) {
        int c = G >> 4, kb = (G & 15) * 64;
#pragma unroll
        for (int nt = 0; nt < 2; ++nt)
#pragma unroll
            for (int ks = 0; ks < 2; ++ks) {
                int rowb = c * 256 + wn * 64 + nt * 32 + l31;
                bB[bank][nt][ks] = *(const i32x4*)(Bq + (size_t)rowb * 1024 + kb + ks * 32 + l5 * 16);
            }
    };
    auto EPI = [&](int c) {
#pragma unroll
        for (int mt = 0; mt < 2; ++mt) {
            int rl = wm * 64 + mt * 32 + 4 * l5;
            float fr[16];
#pragma unroll
            for (int r = 0; r < 16; ++r) fr[r] = sc * factsh[rl + (r & 3) + 8 * (r >> 2)];
#pragma unroll
            for (int nt = 0; nt < 2; ++nt) {
                int col = c * 256 + wn * 64 + nt * 32 + l31;
                float bv = bias[col];
#pragma unroll
                for (int r = 0; r < 16; ++r) {
                    int grow = tm * 128 + rl + (r & 3) + 8 * (r >> 2);
                    out[(size_t)grow * 1024 + col] = (float)acc[mt][nt][r] * fr[r] + bv;
                }
            }
        }
    };

    LDA(0, 0);
    LDB(0, 0);
#pragma unroll
    for (int G = 0; G < 64; ++G) {
        const int cur = G & 1;
        if ((G & 15) == 0) {
#pragma unroll
            for (int i = 0; i < 2; ++i)
#pragma unroll
                for (int j = 0; j < 2; ++j)
#pragma unroll
                    for (int k = 0; k < 16; ++k) acc[i][j][k] = 0;
        }
        if (G < 63) { LDB(G + 1, cur ^ 1); LDA(G + 1, cur ^ 1); }
        __builtin_amdgcn_s_setprio(1);
#pragma unroll
        for (int ks = 0; ks < 2; ++ks)
#pragma unroll
            for (int mt = 0; mt < 2; ++mt)
#pragma unroll
                for (int nt = 0; nt < 2; ++nt)
                    acc[mt][nt] = __builtin_amdgcn_mfma_i32_32x32x32_i8(
                        aB[cur][mt][ks], bB[cur][nt][ks], acc[mt][nt], 0, 0, 0);
        __builtin_amdgcn_s_setprio(0);
        if ((G & 15) == 15) EPI(G >> 4);
    }
}

extern "C" void kernel_launch(void* const* d_in, const int* in_sizes, int n_in,
                              void* d_out, int out_size, void* d_ws, size_t ws_size,
                              hipStream_t stream) {
    const float* x    = (const float*)d_in[0];
    const float* w    = (const float*)d_in[1];
    const float* bias = (const float*)d_in[2];
    float* out = (float*)d_out;
    char* ws = (char*)d_ws;

    double* partials = (double*)ws;
    float*  scale_f  = (float*)(ws + WS_SCALEF);
    int8_t* qw       = (int8_t*)(ws + WS_QW);

    k_wpart<<<256, 256, 0, stream>>>(w, partials);
    k_wquant<<<512, 256, 0, stream>>>(w, partials, qw, scale_f);
    k_mega<<<256, 512, 0, stream>>>(x, qw, scale_f, bias, out);
}

// Round 12
// 104.573 us; speedup vs baseline: 1.3730x; 1.3730x over previous
//
#include <hip/hip_runtime.h>
#include <stdint.h>

using i32x4  = __attribute__((ext_vector_type(4))) int;
using i32x16 = __attribute__((ext_vector_type(16))) int;

// ---------------- ws layout ----------------
#define WS_SCALED   2048
#define WS_SCALEF   2056
#define WS_FACT     4096
#define WS_XQ       (1u << 20)
#define WS_QW       ((1u << 20) + (32u << 20))

// ---------------- kernel 1: fused aquant (blocks 0..8191) + wabs partials (8192..8447) ----
__device__ inline int q8pack(float4 f, float as) {
    int a = (int)fminf(fmaxf(rintf(f.x * as), -128.0f), 127.0f);
    int b = (int)fminf(fmaxf(rintf(f.y * as), -128.0f), 127.0f);
    int c = (int)fminf(fmaxf(rintf(f.z * as), -128.0f), 127.0f);
    int d = (int)fminf(fmaxf(rintf(f.w * as), -128.0f), 127.0f);
    return (a & 0xff) | ((b & 0xff) << 8) | ((c & 0xff) << 16) | ((d & 0xff) << 24);
}

__global__ __launch_bounds__(256) void k_fused1(const float* __restrict__ x,
                                                const float* __restrict__ w,
                                                int8_t* __restrict__ xq,
                                                float* __restrict__ fact,
                                                double* __restrict__ partials) {
    int t = threadIdx.x;
    if (blockIdx.x >= 8192) {
        int b = blockIdx.x - 8192;
        const float4* w4 = (const float4*)(w + b * 4096);
        double s = 0.0;
#pragma unroll
        for (int i = 0; i < 4; ++i) {
            float4 v = w4[i * 256 + t];
            s += (double)fabsf(v.x) + (double)fabsf(v.y) +
                 (double)fabsf(v.z) + (double)fabsf(v.w);
        }
#pragma unroll
        for (int off = 32; off > 0; off >>= 1) s += __shfl_down(s, off, 64);
        __shared__ double lds[4];
        if ((t & 63) == 0) lds[t >> 6] = s;
        __syncthreads();
        if (t == 0) partials[b] = ((lds[0] + lds[1]) + (lds[2] + lds[3]));
        return;
    }
    int wid = t >> 6;
    int lane = t & 63;
    int token = blockIdx.x * 4 + wid;
    const float* xr = x + (size_t)token * 1024;
    float4 v[4];
    float m = 0.0f;
#pragma unroll
    for (int c = 0; c < 4; ++c) {
        v[c] = *(const float4*)(xr + c * 256 + lane * 4);
        m = fmaxf(m, fmaxf(fmaxf(fabsf(v[c].x), fabsf(v[c].y)),
                           fmaxf(fabsf(v[c].z), fabsf(v[c].w))));
    }
#pragma unroll
    for (int off = 32; off > 0; off >>= 1) m = fmaxf(m, __shfl_xor(m, off, 64));
    m = fmaxf(m, 1e-5f);
    float as = 127.0f / m;
    int* xqo = (int*)xq;
#pragma unroll
    for (int c = 0; c < 4; ++c)
        xqo[token * 256 + c * 64 + lane] = q8pack(v[c], as);
    if (lane == 0) fact[token] = 1.0f / as;
}

// ---------------- kernel 2: fused scale-reduce (redundant, deterministic) + wquant ----
__global__ __launch_bounds__(256) void k_fused2(const float* __restrict__ w,
                                                const double* __restrict__ partials,
                                                int8_t* __restrict__ qw,
                                                float* __restrict__ scale_f) {
    int t = threadIdx.x;
    double s = partials[t];
#pragma unroll
    for (int off = 32; off > 0; off >>= 1) s += __shfl_down(s, off, 64);
    __shared__ double lds[4];
    if ((t & 63) == 0) lds[t >> 6] = s;
    __syncthreads();
    __shared__ double sc_sh;
    if (t == 0) {
        double m = ((lds[0] + lds[1]) + (lds[2] + lds[3])) / 1048576.0;
        if (m < 1e-5) m = 1e-5;
        sc_sh = m;
        if (blockIdx.x == 0) *scale_f = (float)m;
    }
    __syncthreads();
    double half_s = 0.5 * sc_sh;

    int idx = blockIdx.x * 2048 + t * 8;
    float4 v0 = *(const float4*)(w + idx);
    float4 v1 = *(const float4*)(w + idx + 4);
    float f[8] = {v0.x, v0.y, v0.z, v0.w, v1.x, v1.y, v1.z, v1.w};
    union { char c[8]; int2 p; } u;
#pragma unroll
    for (int i = 0; i < 8; ++i) {
        char q = 0;
        if ((double)fabsf(f[i]) > half_s) q = (f[i] > 0.0f) ? 1 : -1;
        u.c[i] = q;
    }
    *(int2*)(qw + idx) = u.p;
}

// ---------------- kernel 3: i8 GEMM, r7 schedule + fragment-order LDS (0 conflicts) ----
// BM=128, BN=256, BK=64; 512 thr = 8 waves (2M x 4N), per-wave 64x64 (2x2 of 32x32x32).
// LDS 72 KB = 3 rotating buffers x (A 8KB | B 16KB), stored in MFMA-FRAGMENT ORDER:
//   A frag (tile,ks):  Abase + tile*2048 + ks*1024 + lane*16   (tile = wm*2+mt)
//   B frag (wn,nt,ks): Bbase + wn*4096 + nt*2048 + ks*1024 + lane*16
// -> every ds_read_b128 is a lane-linear 1KB burst: zero bank conflicts, no swizzle.
// Staging: gl_lds linear dest; per-lane GLOBAL source permuted to fragment order.
// Schedule identical to r7: stage(t+2) | vmcnt(3) | s_barrier | reads | MFMA | ...

__device__ __forceinline__ void gl_lds16(const void* g, void* l) {
    __builtin_amdgcn_global_load_lds((const __attribute__((address_space(1))) void*)g,
                                     (__attribute__((address_space(3))) void*)l, 16, 0, 0);
}

__global__ __launch_bounds__(512, 2) void k_gemm8(const int8_t* __restrict__ A,
                                                  const int8_t* __restrict__ B,
                                                  const float* __restrict__ fact,
                                                  const float* __restrict__ scale_f,
                                                  const float* __restrict__ bias,
                                                  float* __restrict__ out) {
    __shared__ int8_t smem[73728];          // 3 x (A 8192 | B 16384)

    const int tid  = threadIdx.x;
    const int lane = tid & 63;
    const int wid  = tid >> 6;
    const int wm   = wid >> 2;              // 0..1
    const int wn   = wid & 3;               // 0..3
    const int l31  = lane & 31;
    const int l5   = lane >> 5;

    // XCD-aware bijective swizzle (1024 % 8 == 0)
    int bid = blockIdx.x;
    int swz = (bid & 7) * 128 + (bid >> 3);
    int tm = swz >> 2;                      // 0..255
    int tn = swz & 3;                       // 0..3

    const int8_t* Ag = A + (size_t)tm * 128 * 1024;
    const int8_t* Bg = B + (size_t)tn * 256 * 1024;

    // staging source offsets (fragment-order): thread tid writes LDS byte tid*16
    const int sj  = tid >> 5;               // fragment id 0..15
    const int sl  = tid & 31;               // l31 within fragment
    // A: frag sj = tile*4 + ks*2 + l5
    const int gA = ((sj >> 2) * 32 + sl) * 1024 + ((sj >> 1) & 1) * 32 + (sj & 1) * 16;
    // B call c (c=0,1): frag j = c*16+sj = wn*8 + nt*4 + ks*2 + l5
    const int gB0 = ((sj >> 3) * 64 + (((sj >> 2) & 1) * 32) + sl) * 1024 + ((sj >> 1) & 1) * 32 + (sj & 1) * 16;
    const int gB1 = (((16 + sj) >> 3) * 64 + ((((16 + sj) >> 2) & 1) * 32) + sl) * 1024 + ((sj >> 1) & 1) * 32 + (sj & 1) * 16;

    auto stage = [&](int buf, int kb) {
        int8_t* base = smem + buf * 24576;
        gl_lds16(Ag + gA + kb,        base + tid * 16);
        gl_lds16(Bg + gB0 + kb,       base + 8192 + tid * 16);
        gl_lds16(Bg + gB1 + kb,       base + 16384 + tid * 16);
    };
    auto ldA = [&](int buf, int mt, int ks) -> i32x4 {
        return *(const i32x4*)(smem + buf * 24576 + (wm * 2 + mt) * 2048 + ks * 1024 + lane * 16);
    };
    auto ldB = [&](int buf, int nt, int ks) -> i32x4 {
        return *(const i32x4*)(smem + buf * 24576 + 8192 + wn * 4096 + nt * 2048 + ks * 1024 + lane * 16);
    };

    i32x16 acc[2][2];
#pragma unroll
    for (int i = 0; i < 2; ++i)
#pragma unroll
        for (int j = 0; j < 2; ++j)
#pragma unroll
            for (int k = 0; k < 16; ++k) acc[i][j][k] = 0;

    // prologue: batches for K-tiles 0 and 1
    stage(0, 0);
    stage(1, 64);
    asm volatile("s_waitcnt vmcnt(3)" ::: "memory");   // my batch0 landed
    __builtin_amdgcn_s_barrier();                      // all waves' batch0 landed

    i32x4 aR[2][2], bR[2][2];

#pragma unroll
    for (int t = 0; t < 16; ++t) {
        const int buf = t % 3;

#pragma unroll
        for (int mt = 0; mt < 2; ++mt)
#pragma unroll
            for (int ks = 0; ks < 2; ++ks) aR[mt][ks] = ldA(buf, mt, ks);
#pragma unroll
        for (int nt = 0; nt < 2; ++nt)
#pragma unroll
            for (int ks = 0; ks < 2; ++ks) bR[nt][ks] = ldB(buf, nt, ks);

        if (t < 14) stage((t + 2) % 3, (t + 2) * 64);

        if (t <= 13) asm volatile("s_waitcnt vmcnt(3) lgkmcnt(0)" ::: "memory");
        else         asm volatile("s_waitcnt vmcnt(0) lgkmcnt(0)" ::: "memory");
        __builtin_amdgcn_s_barrier();

        __builtin_amdgcn_s_setprio(1);
#pragma unroll
        for (int ks = 0; ks < 2; ++ks)
#pragma unroll
            for (int mt = 0; mt < 2; ++mt)
#pragma unroll
                for (int nt = 0; nt < 2; ++nt)
                    acc[mt][nt] = __builtin_amdgcn_mfma_i32_32x32x32_i8(
                        aR[mt][ks], bR[nt][ks], acc[mt][nt], 0, 0, 0);
        __builtin_amdgcn_s_setprio(0);
    }

    // ---- epilogue: direct stores ----
    const float sc = *scale_f;
#pragma unroll
    for (int mt = 0; mt < 2; ++mt) {
        int rbase = tm * 128 + wm * 64 + mt * 32 + 4 * l5;
        float fr[16];
#pragma unroll
        for (int r = 0; r < 16; ++r)
            fr[r] = sc * fact[rbase + (r & 3) + 8 * (r >> 2)];
#pragma unroll
        for (int nt = 0; nt < 2; ++nt) {
            int c = tn * 256 + wn * 64 + nt * 32 + l31;
            float bv = bias[c];
#pragma unroll
            for (int r = 0; r < 16; ++r) {
                int row = rbase + (r & 3) + 8 * (r >> 2);
                out[(size_t)row * 1024 + c] = (float)acc[mt][nt][r] * fr[r] + bv;
            }
        }
    }
}

extern "C" void kernel_launch(void* const* d_in, const int* in_sizes, int n_in,
                              void* d_out, int out_size, void* d_ws, size_t ws_size,
                              hipStream_t stream) {
    const float* x    = (const float*)d_in[0];
    const float* w    = (const float*)d_in[1];
    const float* bias = (const float*)d_in[2];
    float* out = (float*)d_out;
    char* ws = (char*)d_ws;

    double* partials = (double*)ws;
    float*  scale_f  = (float*)(ws + WS_SCALEF);
    float*  fact     = (float*)(ws + WS_FACT);
    int8_t* xq       = (int8_t*)(ws + WS_XQ);
    int8_t* qw       = (int8_t*)(ws + WS_QW);

    k_fused1<<<8448, 256, 0, stream>>>(x, w, xq, fact, partials);
    k_fused2<<<512, 256, 0, stream>>>(w, partials, qw, scale_f);
    k_gemm8<<<1024, 512, 0, stream>>>(xq, qw, fact, scale_f, bias, out);
}